// Round 14
// baseline (31.574 us; speedup 1.0000x reference)
//
#include <hip/hip_runtime.h>

// B=1048576, N=5, H=2, CLS=24, OUT=5.  h0=c0=0 -> w_hh dead, f-gate dead.
// Round-13 resubmit (infra failure; kernel never ran). PERSISTENT blocks +
// software prefetch. All four previous designs (LDS/shfl/ILP/permlane)
// converge at ~30us with all pipes <45% and occupancy 29-41%: short-lived
// workgroups (~2-4us) mean 8-16 sequential block generations, ramp/drain
// bubbles, and lockstep load bursts. This version: grid=1024 (4 blocks/CU,
// ONE generation), each wave loops 4x over 64-elem chunks; iter k+1's 12
// loads are issued between iter k's LSTM (last x/oth use) and iter k's
// FC/store phase -> HBM latency hides under compute.
// Core compute = v11 (permlane32_swap + 32x32x16 MFMA, HW-validated).

constexpr int Bc    = 1048576;
constexpr int Nc    = 5;
constexpr int NBLK  = 1024;                 // 4 blocks/CU
constexpr int NITER = Bc / (NBLK * 256);    // 4

typedef __attribute__((ext_vector_type(8))) short bf16x8;
typedef __attribute__((ext_vector_type(16))) float f32x16;

__device__ __forceinline__ unsigned cvtpk(float lo, float hi) {
    unsigned r;
    asm("v_cvt_pk_bf16_f32 %0, %1, %2" : "=v"(r) : "v"(lo), "v"(hi));
    return r;
}
// v_permlane32_swap_b32 x, y:  x.lanes[32:63] <-> y.lanes[0:31]
__device__ __forceinline__ void swap32(unsigned &x, unsigned &y) {
    asm("v_permlane32_swap_b32 %0, %1" : "+v"(x), "+v"(y));
}
__device__ __forceinline__ float fast_sigmoid(float x) {
    return __builtin_amdgcn_rcpf(1.0f + __expf(-x));
}
// sigmoid(a)*tanh(b) with a single rcp
__device__ __forceinline__ float sigtanh(float a, float b) {
    float ea = __expf(-a);
    float eb = __expf(2.0f * b);
    return (eb - 1.0f) * __builtin_amdgcn_rcpf((eb + 1.0f) * (1.0f + ea));
}
__device__ __forceinline__ bf16x8 mk_frag(unsigned a, unsigned b,
                                          unsigned c, unsigned d) {
    union { uint4 u; bf16x8 v; } x;
    x.u = make_uint4(a, b, c, d);
    return x.v;
}
__device__ __forceinline__ bf16x8 pack_row8(const float* row, bool valid) {
    unsigned h0 = 0, h1 = 0, h2 = 0, h3 = 0;
    if (valid) {
        float4 a = *reinterpret_cast<const float4*>(row);
        float4 b = *reinterpret_cast<const float4*>(row + 4);
        h0 = cvtpk(a.x, a.y); h1 = cvtpk(a.z, a.w);
        h2 = cvtpk(b.x, b.y); h3 = cvtpk(b.z, b.w);
    }
    return mk_frag(h0, h1, h2, h3);
}
__device__ __forceinline__ void load_inputs(const float* __restrict__ seqs,
                                            const float* __restrict__ others,
                                            int e, float2 (&x)[Nc], float2 (&oth)[7]) {
#pragma unroll
    for (int n = 0; n < Nc; n++)
        x[n] = *reinterpret_cast<const float2*>(seqs + ((size_t)n * Bc + e) * 2);
    const float2* op = reinterpret_cast<const float2*>(others + (size_t)e * 14);
#pragma unroll
    for (int j = 0; j < 7; j++) oth[j] = op[j];
}

__global__ __launch_bounds__(256) void fused_rnn_mlp_v13(
    const float* __restrict__ seqs,    // [N,1,B,2]
    const float* __restrict__ others,  // [1,B,14]
    const float* __restrict__ w_ih,    // [N,8,2]
    const float* __restrict__ b_ih,    // [N,8]
    const float* __restrict__ b_hh,    // [N,8]
    const float* __restrict__ w1,      // [24,24]
    const float* __restrict__ b1,      // [24]
    const float* __restrict__ w2,      // [5,24]
    const float* __restrict__ b2,      // [5]
    float* __restrict__ out)           // [B,5]
{
    const int tid  = threadIdx.x;
    const int lane = tid & 63;
    const int lo31 = lane & 31;        // elem-in-tile / weight row
    const int kh   = lane >> 5;        // 0: lanes 0-31, 1: lanes 32-63

    // ---------- loop-invariant: A-fragments + C1 bias init ----------
    const bf16x8 A1a = pack_row8(w1 + lo31 * 24 + 8 * kh, lo31 < 24);
    const bf16x8 A1b = pack_row8(w1 + lo31 * 24 + 16, (lo31 < 24) && (kh == 0));
    const bf16x8 A2a = pack_row8(w2 + lo31 * 24 + 8 * kh, lo31 < 5);
    const bf16x8 A2b = pack_row8(w2 + lo31 * 24 + 16, (lo31 < 5) && (kh == 0));

    f32x16 c1z;
#pragma unroll
    for (int r = 0; r < 16; r++) {
        const int jb = (r & 3) + 8 * (r >> 2);        // row for kh=0
        float v = 0.0f;
        if (jb < 24) v = kh ? b1[jb + 4] : b1[jb];
        c1z[r] = v;
    }
    // combined LSTM biases (uniform s_loads, hoisted)
    float cb[6 * Nc];
#pragma unroll
    for (int n = 0; n < Nc; n++) {
        cb[6*n+0] = b_ih[n*8+0] + b_hh[n*8+0];
        cb[6*n+1] = b_ih[n*8+1] + b_hh[n*8+1];
        cb[6*n+2] = b_ih[n*8+4] + b_hh[n*8+4];
        cb[6*n+3] = b_ih[n*8+5] + b_hh[n*8+5];
        cb[6*n+4] = b_ih[n*8+6] + b_hh[n*8+6];
        cb[6*n+5] = b_ih[n*8+7] + b_hh[n*8+7];
    }

    // ---------- prefetch iteration 0 ----------
    float2 x[Nc], oth[7];
    load_inputs(seqs, others, blockIdx.x * 256 + tid, x, oth);

#pragma unroll 1
    for (int k = 0; k < NITER; k++) {
        const int cbase = (k * NBLK + blockIdx.x) * 256;
        const int wbase = cbase + (tid >> 6) * 64;

        // ---------- LSTM (one step, h0=c0=0); pack feats into d[12] ----------
        unsigned d[12];
#pragma unroll
        for (int n = 0; n < Nc; n++) {
            const float* w = w_ih + n * 16;   // gate rows i(0,1) f(2,3) g(4,5) o(6,7)
            float gi0 = fmaf(x[n].x, w[0],  fmaf(x[n].y, w[1],  cb[6*n+0]));
            float gi1 = fmaf(x[n].x, w[2],  fmaf(x[n].y, w[3],  cb[6*n+1]));
            float gg0 = fmaf(x[n].x, w[8],  fmaf(x[n].y, w[9],  cb[6*n+2]));
            float gg1 = fmaf(x[n].x, w[10], fmaf(x[n].y, w[11], cb[6*n+3]));
            float go0 = fmaf(x[n].x, w[12], fmaf(x[n].y, w[13], cb[6*n+4]));
            float go1 = fmaf(x[n].x, w[14], fmaf(x[n].y, w[15], cb[6*n+5]));
            float c0 = sigtanh(gi0, gg0);
            float c1 = sigtanh(gi1, gg1);
            d[n] = cvtpk(sigtanh(go0, c0), sigtanh(go1, c1));
        }
#pragma unroll
        for (int j = 0; j < 7; j++)
            d[5 + j] = cvtpk(oth[j].x, oth[j].y);

        // ---------- prefetch iter k+1 (after last x/oth read, before FC) ----------
        if (k + 1 < NITER)
            load_inputs(seqs, others, ((k + 1) * NBLK + blockIdx.x) * 256 + tid,
                        x, oth);

        // ---------- FC1 B-fragments via permlane32_swap (dual-output) ----------
        unsigned b0a[4], b1a[4], b0b[4], b1b[4];
#pragma unroll
        for (int i = 0; i < 4; i++) {
            b0a[i] = d[i];     b1a[i] = d[4 + i];  swap32(b0a[i], b1a[i]);
            b0b[i] = d[8 + i]; b1b[i] = 0u;        swap32(b0b[i], b1b[i]);
        }

        // ---------- per tile: FC1 -> FC2 -> sigmoid -> store ----------
#pragma unroll
        for (int t = 0; t < 2; t++) {
            f32x16 acc = c1z;
            acc = __builtin_amdgcn_mfma_f32_32x32x16_bf16(
                A1a, mk_frag(t ? b1a[0] : b0a[0], t ? b1a[1] : b0a[1],
                             t ? b1a[2] : b0a[2], t ? b1a[3] : b0a[3]),
                acc, 0, 0, 0);
            acc = __builtin_amdgcn_mfma_f32_32x32x16_bf16(
                A1b, mk_frag(t ? b1b[0] : b0b[0], t ? b1b[1] : b0b[1],
                             t ? b1b[2] : b0b[2], t ? b1b[3] : b0b[3]),
                acc, 0, 0, 0);

            unsigned p0 = cvtpk(fmaxf(acc[0],  0.f), fmaxf(acc[1],  0.f));
            unsigned p1 = cvtpk(fmaxf(acc[2],  0.f), fmaxf(acc[3],  0.f));
            unsigned p2 = cvtpk(fmaxf(acc[4],  0.f), fmaxf(acc[5],  0.f));
            unsigned p3 = cvtpk(fmaxf(acc[6],  0.f), fmaxf(acc[7],  0.f));
            unsigned p4 = cvtpk(fmaxf(acc[8],  0.f), fmaxf(acc[9],  0.f));
            unsigned p5 = cvtpk(fmaxf(acc[10], 0.f), fmaxf(acc[11], 0.f));
            unsigned w0 = p0, w2 = p2;  swap32(w0, w2);
            unsigned w1v = p1, w3 = p3; swap32(w1v, w3);
            unsigned u0 = p4, u2 = 0u;  swap32(u0, u2);
            unsigned u1 = p5, u3 = 0u;  swap32(u1, u3);

            f32x16 c2;
#pragma unroll
            for (int r = 0; r < 16; r++) c2[r] = 0.0f;
            c2[0] = kh ? b2[4] : b2[0];
            if (!kh) { c2[1] = b2[1]; c2[2] = b2[2]; c2[3] = b2[3]; }
            c2 = __builtin_amdgcn_mfma_f32_32x32x16_bf16(
                A2a, mk_frag(w0, w1v, w2, w3), c2, 0, 0, 0);
            c2 = __builtin_amdgcn_mfma_f32_32x32x16_bf16(
                A2b, mk_frag(u0, u1, u2, u3), c2, 0, 0, 0);

            const float s0 = fast_sigmoid(c2[0]);
            const float s1 = fast_sigmoid(c2[1]);
            const float s2 = fast_sigmoid(c2[2]);
            const float s3 = fast_sigmoid(c2[3]);
            const int et = wbase + t * 32 + lo31;
            float* o = out + (size_t)et * 5;
            if (kh == 0) {          // rows q=0..3
                o[0] = s0; o[1] = s1; o[2] = s2; o[3] = s3;
            } else {                // row q=4 (reg 0)
                o[4] = s0;
            }
        }
    }
}

extern "C" void kernel_launch(void* const* d_in, const int* in_sizes, int n_in,
                              void* d_out, int out_size, void* d_ws, size_t ws_size,
                              hipStream_t stream) {
    const float* seqs   = (const float*)d_in[0];
    const float* others = (const float*)d_in[1];
    const float* w_ih   = (const float*)d_in[2];
    // d_in[3] = w_hh : dead (h0 = 0)
    const float* b_ih   = (const float*)d_in[4];
    const float* b_hh   = (const float*)d_in[5];
    const float* w1     = (const float*)d_in[6];
    const float* b1     = (const float*)d_in[7];
    const float* w2     = (const float*)d_in[8];
    const float* b2     = (const float*)d_in[9];
    float* out = (float*)d_out;

    dim3 grid(NBLK), block(256);
    fused_rnn_mlp_v13<<<grid, block, 0, stream>>>(
        seqs, others, w_ih, b_ih, b_hh, w1, b1, w2, b2, out);
}